// Round 1
// baseline (647.882 us; speedup 1.0000x reference)
//
#include <hip/hip_runtime.h>
#include <hip/hip_bf16.h>

#define BATCH_N 512
#define CH 256
#define FD 512

typedef __attribute__((ext_vector_type(8))) short short8_t;
typedef __attribute__((ext_vector_type(4))) short short4_t;
typedef __attribute__((ext_vector_type(4))) float f32x4;

// ---- LDS map (bytes) ----
// GEMM1 phase: 4 tiles [256 rows][32 bf16, padded to 80 B] = 20480 each, in [0,81920)
// GEMM2 phase: W bf16 [256][512B rows, XOR-swizzled] @ 0     (131072)
//              XT tile [256 f][32 j, padded 80 B]   @ 131072 (20480)
// softmax:     red @ 151552 (4 KB), red2 @ 155648 (4 KB)
#define OFF_X0 0
#define OFF_A0 20480
#define OFF_X1 40960
#define OFF_A1 61440
#define OFF_W  0
#define OFF_XT 131072
#define OFF_RED 151552
#define OFF_RED2 155648
#define SMEM_BYTES 159744

__device__ __forceinline__ short f2bf(float x) {
    unsigned u = __builtin_bit_cast(unsigned, x);
    u = (u + 0x7fffu + ((u >> 16) & 1u)) >> 16;   // RNE truncate to bf16
    return (short)u;
}

__global__ __launch_bounds__(512, 2)
void topo_attn_kernel(const float* __restrict__ Xg, const float* __restrict__ Ag,
                      float* __restrict__ Og, float* __restrict__ Wg)
{
    extern __shared__ float4 smem4[];
    char* smem = (char*)smem4;

    const int b   = blockIdx.x;
    const int t   = threadIdx.x;
    const int w   = t >> 6;        // wave 0..7
    const int l   = t & 63;
    const int wm  = w >> 2;        // 0..1  (M half)
    const int wn  = w & 3;         // 0..3  (N quarter)
    const int l16 = l & 15;
    const int lg  = l >> 4;        // 0..3

    const float* Xb = Xg + (size_t)b * (CH * FD);

    // ================= GEMM1: S = Xb(256x512) * A^T =================
    f32x4 acc[8][4];
#pragma unroll
    for (int i = 0; i < 8; ++i)
#pragma unroll
        for (int j = 0; j < 4; ++j) acc[i][j] = f32x4{0.f, 0.f, 0.f, 0.f};

    const int srow = w * 32 + (l >> 3);   // + 8*q  -> rows 0..255
    const int scol = 4 * (l & 7);         // float4 col within 32-k tile

    // prologue: stage ks=0 into buf0
    {
#pragma unroll
        for (int q = 0; q < 4; ++q) {
            const int r_ = srow + 8 * q;
            float4 vx = *(const float4*)(Xb + r_ * FD + scol);
            float4 va = *(const float4*)(Ag + r_ * FD + scol);
            short4_t sx, sa;
            sx[0] = f2bf(vx.x); sx[1] = f2bf(vx.y); sx[2] = f2bf(vx.z); sx[3] = f2bf(vx.w);
            sa[0] = f2bf(va.x); sa[1] = f2bf(va.y); sa[2] = f2bf(va.z); sa[3] = f2bf(va.w);
            *(short4_t*)(smem + OFF_X0 + r_ * 80 + 2 * scol) = sx;
            *(short4_t*)(smem + OFF_A0 + r_ * 80 + 2 * scol) = sa;
        }
    }
    __syncthreads();

#pragma unroll 2
    for (int ks = 0; ks < 16; ++ks) {
        float4 px[4], pa[4];
        if (ks < 15) {
#pragma unroll
            for (int q = 0; q < 4; ++q) {
                const int r_ = srow + 8 * q;
                const int f_ = (ks + 1) * 32 + scol;
                px[q] = *(const float4*)(Xb + r_ * FD + f_);
                pa[q] = *(const float4*)(Ag + r_ * FD + f_);
            }
        }
        const char* bx = smem + ((ks & 1) ? OFF_X1 : OFF_X0);
        const char* ba = smem + ((ks & 1) ? OFF_A1 : OFF_A0);
        short8_t af[8], bfr[4];
#pragma unroll
        for (int mf = 0; mf < 8; ++mf)
            af[mf] = *(const short8_t*)(bx + (wm * 128 + mf * 16 + l16) * 80 + 16 * lg);
#pragma unroll
        for (int nf = 0; nf < 4; ++nf)
            bfr[nf] = *(const short8_t*)(ba + (wn * 64 + nf * 16 + l16) * 80 + 16 * lg);
#pragma unroll
        for (int mf = 0; mf < 8; ++mf)
#pragma unroll
            for (int nf = 0; nf < 4; ++nf)
                acc[mf][nf] = __builtin_amdgcn_mfma_f32_16x16x32_bf16(af[mf], bfr[nf], acc[mf][nf], 0, 0, 0);
        if (ks < 15) {
            char* dx = smem + ((ks & 1) ? OFF_X0 : OFF_X1);
            char* da = smem + ((ks & 1) ? OFF_A0 : OFF_A1);
#pragma unroll
            for (int q = 0; q < 4; ++q) {
                const int r_ = srow + 8 * q;
                short4_t sx, sa;
                sx[0] = f2bf(px[q].x); sx[1] = f2bf(px[q].y); sx[2] = f2bf(px[q].z); sx[3] = f2bf(px[q].w);
                sa[0] = f2bf(pa[q].x); sa[1] = f2bf(pa[q].y); sa[2] = f2bf(pa[q].z); sa[3] = f2bf(pa[q].w);
                *(short4_t*)(dx + r_ * 80 + 2 * scol) = sx;
                *(short4_t*)(da + r_ * 80 + 2 * scol) = sa;
            }
        }
        __syncthreads();
    }

    // ================= softmax over j (rows = i) =================
    // acc[mf][nf][r] = S[i][j], i = wm*128+mf*16+lg*4+r, j = wn*64+nf*16+l16
    float* red  = (float*)(smem + OFF_RED);   // [4 wn][256 i] partial max
    float* red2 = (float*)(smem + OFF_RED2);  // [4 wn][256 i] partial sum

#pragma unroll
    for (int mf = 0; mf < 8; ++mf)
#pragma unroll
        for (int r = 0; r < 4; ++r) {
            float m = fmaxf(fmaxf(acc[mf][0][r], acc[mf][1][r]),
                            fmaxf(acc[mf][2][r], acc[mf][3][r]));
            m = fmaxf(m, __shfl_xor(m, 1));
            m = fmaxf(m, __shfl_xor(m, 2));
            m = fmaxf(m, __shfl_xor(m, 4));
            m = fmaxf(m, __shfl_xor(m, 8));
            if (l16 == 0) red[wn * 256 + wm * 128 + mf * 16 + lg * 4 + r] = m;
        }
    __syncthreads();

#pragma unroll
    for (int mf = 0; mf < 8; ++mf)
#pragma unroll
        for (int r = 0; r < 4; ++r) {
            const int il = wm * 128 + mf * 16 + lg * 4 + r;
            const float m = fmaxf(fmaxf(red[il], red[256 + il]),
                                  fmaxf(red[512 + il], red[768 + il]));
            float s = 0.f;
#pragma unroll
            for (int nf = 0; nf < 4; ++nf) {
                float e = __expf(acc[mf][nf][r] - m);
                acc[mf][nf][r] = e;
                s += e;
            }
            s += __shfl_xor(s, 1);
            s += __shfl_xor(s, 2);
            s += __shfl_xor(s, 4);
            s += __shfl_xor(s, 8);
            if (l16 == 0) red2[wn * 256 + il] = s;
        }
    __syncthreads();

    // scale, write W (global fp32) + W-LDS (bf16, XOR-swizzled rows of 512 B)
    float* Wb = Wg + (size_t)b * (CH * CH);
    char*  wl = smem + OFF_W;
#pragma unroll
    for (int mf = 0; mf < 8; ++mf)
#pragma unroll
        for (int r = 0; r < 4; ++r) {
            const int il = wm * 128 + mf * 16 + lg * 4 + r;
            const float tot = red2[il] + red2[256 + il] + red2[512 + il] + red2[768 + il];
            const float inv = 1.0f / tot;
#pragma unroll
            for (int nf = 0; nf < 4; ++nf) {
                const float v = acc[mf][nf][r] * inv;
                const int j_ = wn * 64 + nf * 16 + l16;
                Wb[il * 256 + j_] = v;
                *(short*)(wl + il * 512 + ((2 * j_) ^ ((il & 7) << 4))) = f2bf(v);
            }
        }
    __syncthreads();

    // ================= GEMM2: out = W(256x256) * Xb(256x512) =================
    float* Ob = Og + (size_t)b * (CH * FD);
    char*  xt = smem + OFF_XT;
    const int floc_base = wn * 16 + l16;   // + q*64 -> f row in XT tile
    const int jl = wm * 16 + lg * 4;       // j base within 32-j tile
    const int swz = (l16 & 7) << 4;

#pragma unroll 1
    for (int fc = 0; fc < 2; ++fc) {
        f32x4 acc2[8][4];
#pragma unroll
        for (int i = 0; i < 8; ++i)
#pragma unroll
            for (int j = 0; j < 4; ++j) acc2[i][j] = f32x4{0.f, 0.f, 0.f, 0.f};

#pragma unroll 1
        for (int jc = 0; jc < 8; ++jc) {
            // stage XT[f][j] = Xb[jc*32+j][fc*256+f]  (transpose, fp32->bf16)
#pragma unroll
            for (int q = 0; q < 4; ++q) {
                const int floc = q * 64 + floc_base;
                short4_t sv;
#pragma unroll
                for (int e = 0; e < 4; ++e) {
                    const float v = Xb[(size_t)(jc * 32 + jl + e) * FD + fc * 256 + floc];
                    sv[e] = f2bf(v);
                }
                *(short4_t*)(xt + floc * 80 + 2 * jl) = sv;
            }
            __syncthreads();

            short8_t af[8], bfr[4];
#pragma unroll
            for (int mf = 0; mf < 8; ++mf)
                af[mf] = *(const short8_t*)(wl + (wm * 128 + mf * 16 + l16) * 512
                                               + ((jc * 64 + 16 * lg) ^ swz));
#pragma unroll
            for (int nf = 0; nf < 4; ++nf)
                bfr[nf] = *(const short8_t*)(xt + (wn * 64 + nf * 16 + l16) * 80 + 16 * lg);
#pragma unroll
            for (int mf = 0; mf < 8; ++mf)
#pragma unroll
                for (int nf = 0; nf < 4; ++nf)
                    acc2[mf][nf] = __builtin_amdgcn_mfma_f32_16x16x32_bf16(af[mf], bfr[nf], acc2[mf][nf], 0, 0, 0);
            __syncthreads();
        }

#pragma unroll
        for (int mf = 0; mf < 8; ++mf)
#pragma unroll
            for (int nf = 0; nf < 4; ++nf)
#pragma unroll
                for (int r = 0; r < 4; ++r) {
                    const int il = wm * 128 + mf * 16 + lg * 4 + r;
                    const int f_ = fc * 256 + wn * 64 + nf * 16 + l16;
                    Ob[il * FD + f_] = acc2[mf][nf][r];
                }
    }
}

extern "C" void kernel_launch(void* const* d_in, const int* in_sizes, int n_in,
                              void* d_out, int out_size, void* d_ws, size_t ws_size,
                              hipStream_t stream) {
    const float* X = (const float*)d_in[0];
    const float* A = (const float*)d_in[1];
    float* out = (float*)d_out;                              // [512,256,512]
    float* W   = out + (size_t)BATCH_N * CH * FD;            // [512,256,256]

    (void)hipFuncSetAttribute((const void*)topo_attn_kernel,
                              hipFuncAttributeMaxDynamicSharedMemorySize, SMEM_BYTES);
    topo_attn_kernel<<<dim3(BATCH_N), dim3(512), SMEM_BYTES, stream>>>(X, A, out, W);
}